// Round 4
// baseline (548.970 us; speedup 1.0000x reference)
//
#include <hip/hip_runtime.h>
#include <math.h>

// AxileAttention: out = softmax((X@Wq+bq)*(X@Wk+bk), -1) * (X@Wv+bv), per (b,c).
// B=8 C=64 H=256 W=256, fp32 in/out.
//
// Round 11: FUSED single K-pass. R10 post-mortem: dbuf worked (454->307) but
// 32 lockstep barrier-iterations x 2 passes remain; MFMA 16.5% / VALU 22% /
// ~60% no-issue cycles. Fuse q,k,v into one 16-iteration pass (7 MFMA/kt:
// 3q+3k+1v). A (X) no longer staged in LDS: each lane loads its MFMA A-frag
// directly from global (row=lane&31, 32B/lane; 8 waves read identical addrs ->
// L1 broadcast), converts to f16 hi/lo in-reg for the NEXT kt during current
// MFMA (convert VALU = latency shadow, R9 lesson). X read once (-134MB),
// barriers 32->16, A ds_write/read gone. M=32 blocks (grid 4096, 8 waves,
// 32x32 wave tile) -> acc 48 f32, ~110 VGPR. LDS = 5 W planes dbuf = 80KB
// exactly -> 2 blocks/CU. Softmax scratch aliases buf0 after the loop.
// prep_w (W->f16 hi/lo fragment planes in d_ws) unchanged; R8 fallback kept.

#define Bn 8
#define Cn 64
#define Hn 256
#define Wn 256

typedef _Float16 f16x8 __attribute__((ext_vector_type(8)));
typedef _Float16 f16x4 __attribute__((ext_vector_type(4)));
typedef float    f32x16 __attribute__((ext_vector_type(16)));

#define MFMA(a, b, c) __builtin_amdgcn_mfma_f32_32x32x16_f16((a), (b), (c), 0, 0, 0)

// ws layout: plane(c,kt,p) = ((c*16+kt)*5+p) * 8192 bytes, p: 0=qh 1=ql 2=kh 3=kl 4=vh
// within plane: ntile*1024 + (khalf*32+nl)*16 bytes = f16x8 of rows k0+khalf*8..+8 at col n
#define WS_PLANE_H 4096   // _Float16 elements per plane (8192 B)
#define WS_NEED ((size_t)Cn * 16 * 5 * 8192)

// fused-kernel LDS: two W buffers of 5 planes. 2*5*8192 = 81920 B -> 2 blocks/CU.
#define FPL  8192
#define FBUF 40960

__device__ __forceinline__ void ldst16(const void* g, void* l) {
    __builtin_amdgcn_global_load_lds(
        (const __attribute__((address_space(1))) unsigned int*)g,
        (__attribute__((address_space(3))) unsigned int*)l, 16, 0, 0);
}

__device__ __forceinline__ void cvt_hilo(const float4 a, const float4 b,
                                         f16x8& hi, f16x8& lo) {
    float v[8] = {a.x, a.y, a.z, a.w, b.x, b.y, b.z, b.w};
#pragma unroll
    for (int e = 0; e < 8; ++e) {
        _Float16 hv = (_Float16)v[e];
        hi[e] = hv;
        lo[e] = (_Float16)(v[e] - (float)hv);
    }
}

// ---------------- prep: W (f32) -> fragment-ordered f16 hi/lo planes ----------------
__global__ __launch_bounds__(256) void prep_w(
    const float* __restrict__ wq, const float* __restrict__ wk,
    const float* __restrict__ wv, _Float16* __restrict__ wf)
{
    const int blk = blockIdx.x;          // c*16 + kt
    const int kt  = blk & 15;
    const int c   = blk >> 4;
    const int n   = threadIdx.x;         // column 0..255
    const int ntile = n >> 5;
    const int nl    = n & 31;

    _Float16* base = wf + (size_t)blk * 5 * WS_PLANE_H;
    const size_t woff = ((size_t)c * Wn + kt * 16) * Wn + n;

#pragma unroll
    for (int mat = 0; mat < 2; ++mat) {      // 0=q, 1=k : hi+lo planes
        const float* Wp = (mat ? wk : wq) + woff;
        float w16[16];
#pragma unroll
        for (int r = 0; r < 16; ++r)
            w16[r] = Wp[(size_t)r * Wn];
        _Float16* hip = base + (mat * 2) * WS_PLANE_H + ntile * 512;
        _Float16* lop = hip + WS_PLANE_H;
#pragma unroll
        for (int h2 = 0; h2 < 2; ++h2) {
            f16x8 hi8, lo8;
#pragma unroll
            for (int e = 0; e < 8; ++e) {
                const float wv_ = w16[h2 * 8 + e];
                _Float16 hv = (_Float16)wv_;
                hi8[e] = hv;
                lo8[e] = (_Float16)(wv_ - (float)hv);
            }
            *(f16x8*)(hip + (h2 * 32 + nl) * 8) = hi8;
            *(f16x8*)(lop + (h2 * 32 + nl) * 8) = lo8;
        }
    }
    {   // v: hi only (plane 4)
        const float* Wp = wv + woff;
        float w16[16];
#pragma unroll
        for (int r = 0; r < 16; ++r)
            w16[r] = Wp[(size_t)r * Wn];
        _Float16* vp = base + 4 * WS_PLANE_H + ntile * 512;
#pragma unroll
        for (int h2 = 0; h2 < 2; ++h2) {
            f16x8 hi8;
#pragma unroll
            for (int e = 0; e < 8; ++e)
                hi8[e] = (_Float16)w16[h2 * 8 + e];
            *(f16x8*)(vp + (h2 * 32 + nl) * 8) = hi8;
        }
    }
}

// ---------------- main: fused single-pass, prepped-W, dbuf ----------------
__global__ __launch_bounds__(512, 4) void axile_attn_fused(
    const float* __restrict__ x,
    const _Float16* __restrict__ wf,
    const float* __restrict__ bq,
    const float* __restrict__ bk,
    const float* __restrict__ bv,
    float* __restrict__ out)
{
    __shared__ __align__(16) char lds[2 * FBUF];

    const int tid  = threadIdx.x;
    const int ncol = tid >> 6;     // wave id = 32-col strip 0..7
    const int lane = tid & 63;
    const int h    = lane >> 5;
    const int l31  = lane & 31;

    // blk = (ht*8 + b)*64 + c : c low bits -> XCD affinity per channel
    // (W planes + bias slices L2-resident per XCD); b varies within a round
    // (same (c,ht) bias slice shared by co-resident blocks).
    const int blk = blockIdx.x;
    const int c   = blk & 63;
    const int j   = blk >> 6;      // ht*8 + b
    const int b   = j & 7;
    const int h0  = (j >> 3) * 32; // 32-row tile

    // A-fragment source: lane reads row (lane&31), k-half (lane>>5)*8.
    const float* xrow = x + ((size_t)(b * Cn + c) * Hn + h0 + l31) * Wn + h * 8;
    const _Float16* wfc = wf + (size_t)c * 16 * 5 * WS_PLANE_H;

    f32x16 accq, acck, accv;
#pragma unroll
    for (int r = 0; r < 16; ++r) {
        accq[r] = 0.f;
        acck[r] = 0.f;
        accv[r] = 0.f;
    }

    // ---- prologue: stage W tile 0 into buf0; load+convert A-frag 0 ----
#pragma unroll
    for (int p = 0; p < 5; ++p)
        ldst16(wfc + p * WS_PLANE_H + tid * 8, lds + p * FPL + tid * 16);
    f16x8 ah, al;
    {
        const float4 xa = *(const float4*)(xrow);
        const float4 xb = *(const float4*)(xrow + 4);
        cvt_hilo(xa, xb, ah, al);
    }
    __syncthreads();

    // ================= fused K-loop: 16 iterations, 7 MFMA each =================
    int curo = 0;
    for (int kt = 0; kt < 16; ++kt) {
        const int nxto = curo ^ FBUF;
        float4 xa, xb;
        if (kt < 15) {
            // X regs load FIRST (its consumer waits vmcnt(5), W stays in flight)
            xa = *(const float4*)(xrow + (kt + 1) * 16);
            xb = *(const float4*)(xrow + (kt + 1) * 16 + 4);
            const _Float16* wsp = wfc + (size_t)(kt + 1) * 5 * WS_PLANE_H;
#pragma unroll
            for (int p = 0; p < 5; ++p)
                ldst16(wsp + p * WS_PLANE_H + tid * 8,
                       lds + nxto + p * FPL + tid * 16);
        }

        const char* bb = lds + curo + ncol * 1024 + lane * 16;
        const f16x8 bqh = *(const f16x8*)(bb + 0 * FPL);
        const f16x8 bql = *(const f16x8*)(bb + 1 * FPL);
        const f16x8 bkh = *(const f16x8*)(bb + 2 * FPL);
        const f16x8 bkl = *(const f16x8*)(bb + 3 * FPL);
        const f16x8 bvh = *(const f16x8*)(bb + 4 * FPL);

        accq = MFMA(ah, bqh, accq);
        accq = MFMA(al, bqh, accq);
        accq = MFMA(ah, bql, accq);
        acck = MFMA(ah, bkh, acck);
        acck = MFMA(al, bkh, acck);
        acck = MFMA(ah, bkl, acck);
        accv = MFMA(ah, bvh, accv);

        if (kt < 15)
            cvt_hilo(xa, xb, ah, al);   // next-iter A frags; hides X latency
        __syncthreads();                // drains W loads for kt+1; buf swap safe
        curo = nxto;
    }

    // ---- softmax scratch aliases buf0 (all LDS reads done past final barrier) ----
    float* part    = (float*)lds;            // [8 waves][32 rows]
    float* combmax = (float*)(lds + 1024);   // [32]
    float* combsum = (float*)(lds + 1152);   // [32]

    // ---- s = (q+bq)*(k+bk) into accq ----
#pragma unroll
    for (int r = 0; r < 16; ++r) {
        const int row = (r & 3) + 8 * (r >> 2) + 4 * h;
        const int hh  = h0 + row;
        const int vv  = ncol * 32 + l31;
        const size_t bidx = ((size_t)c * Hn + hh) * Wn + vv;
        const float qv = accq[r] + bq[bidx];
        const float kv = acck[r] + bk[bidx];
        accq[r] = qv * kv;
    }

    // ---- row max (reduce over l31; h halves separate) ----
#pragma unroll
    for (int r = 0; r < 16; ++r) {
        float m2 = accq[r];
#pragma unroll
        for (int off = 16; off > 0; off >>= 1)
            m2 = fmaxf(m2, __shfl_xor(m2, off, 64));
        if ((lane & 31) == r) {
            const int row = (r & 3) + 8 * (r >> 2) + 4 * h;
            part[ncol * 32 + row] = m2;
        }
    }
    __syncthreads();
    if (tid < 32) {
        float m = part[tid];
#pragma unroll
        for (int w = 1; w < 8; ++w)
            m = fmaxf(m, part[w * 32 + tid]);
        combmax[tid] = m;
    }
    __syncthreads();

    // ---- e = exp(s - mx); row sum ----
#pragma unroll
    for (int r = 0; r < 16; ++r) {
        const int row = (r & 3) + 8 * (r >> 2) + 4 * h;
        const float mx = combmax[row];
        const float e0 = __expf(accq[r] - mx);
        accq[r] = e0;
        float ps = e0;
#pragma unroll
        for (int off = 16; off > 0; off >>= 1)
            ps += __shfl_xor(ps, off, 64);
        if ((lane & 31) == r)
            part[ncol * 32 + row] = ps;
    }
    __syncthreads();
    if (tid < 32) {
        float s = part[tid];
#pragma unroll
        for (int w = 1; w < 8; ++w)
            s += part[w * 32 + tid];
        combsum[tid] = s;
    }
    __syncthreads();

    // ---- out = e * (v + bv) / sum ----
    float* obase = out + ((size_t)(b * Cn + c) * Hn) * Wn;
#pragma unroll
    for (int r = 0; r < 16; ++r) {
        const int row = (r & 3) + 8 * (r >> 2) + 4 * h;
        const float inv = 1.0f / combsum[row];
        const int hh = h0 + row;
        const int vv = ncol * 32 + l31;
        const size_t bidx = ((size_t)c * Hn + hh) * Wn + vv;
        const float vx = accv[r] + bv[bidx];
        obase[(size_t)hh * Wn + vv] = accq[r] * vx * inv;
    }
}

// ---------------- fallback (R8): in-kernel W conversion, no ws ----------------
#define LDS_ALO 2048
#define LDS_B   4096

__global__ __launch_bounds__(512, 4) void axile_attn_mfma4(
    const float* __restrict__ x,
    const float* __restrict__ wq,
    const float* __restrict__ wk,
    const float* __restrict__ wv,
    const float* __restrict__ bq,
    const float* __restrict__ bk,
    const float* __restrict__ bv,
    float* __restrict__ out)
{
    __shared__ __align__(16) char lds[39424];

    const int tid  = threadIdx.x;
    const int ncol = tid >> 6;
    const int lane = tid & 63;
    const int h    = lane >> 5;
    const int l31  = lane & 31;

    const int blk = blockIdx.x;
    const int c   = blk & 63;
    const int j   = blk >> 6;
    const int b   = j & 7;
    const int h0  = (j >> 3) * 64;

    const float* xbase = x + ((size_t)(b * Cn + c) * Hn + h0) * Wn;
    const float* w_q = wq + (size_t)c * Wn * Wn;
    const float* w_k = wk + (size_t)c * Wn * Wn;
    const float* w_v = wv + (size_t)c * Wn * Wn;

    const int wkh = tid >> 8;
    const int n   = tid & 255;
    const int ntW = n >> 5;
    const int nl  = n & 31;
    const int wfo = ((wkh << 5) | nl) * 16;
    const int am    = tid >> 2;
    const int akq   = tid & 3;
    const int amt   = am >> 5;
    const int alc   = ((akq >> 1) << 5) | (am & 31);
    const int aboff = (akq & 1) * 8;

    f32x16 accq[2], acck[2];
#pragma unroll
    for (int mt = 0; mt < 2; ++mt)
#pragma unroll
        for (int r = 0; r < 16; ++r) {
            accq[mt][r] = 0.f;
            acck[mt][r] = 0.f;
        }

    for (int kt = 0; kt < 16; ++kt) {
        const int k0 = kt * 16;
        __syncthreads();
#pragma unroll
        for (int mat = 0; mat < 2; ++mat) {
            const float* Wp = mat ? w_k : w_q;
            const float* wrow = Wp + (size_t)(k0 + wkh * 8) * Wn + n;
            float w8[8];
#pragma unroll
            for (int r = 0; r < 8; ++r)
                w8[r] = wrow[(size_t)r * Wn];
            f16x8 hi8, lo8;
#pragma unroll
            for (int e = 0; e < 8; ++e) {
                const float wv_ = w8[e];
                _Float16 hv = (_Float16)wv_;
                hi8[e] = hv;
                lo8[e] = (_Float16)(wv_ - (float)hv);
            }
            char* dplane = lds + LDS_B + (mat * 2) * 8192 + ntW * 1024;
            *(f16x8*)(dplane + wfo) = hi8;
            *(f16x8*)(dplane + 8192 + wfo) = lo8;
        }
        if (tid < 256) {
            const float4 xx = *(const float4*)(xbase + (size_t)am * Wn + k0 + akq * 4);
            f16x4 hi4, lo4;
            _Float16 t0 = (_Float16)xx.x; hi4[0] = t0; lo4[0] = (_Float16)(xx.x - (float)t0);
            _Float16 t1 = (_Float16)xx.y; hi4[1] = t1; lo4[1] = (_Float16)(xx.y - (float)t1);
            _Float16 t2 = (_Float16)xx.z; hi4[2] = t2; lo4[2] = (_Float16)(xx.z - (float)t2);
            _Float16 t3 = (_Float16)xx.w; hi4[3] = t3; lo4[3] = (_Float16)(xx.w - (float)t3);
            *(f16x4*)(lds + amt * 1024 + alc * 16 + aboff) = hi4;
            *(f16x4*)(lds + LDS_ALO + amt * 1024 + alc * 16 + aboff) = lo4;
        }
        __syncthreads();

        f16x8 ah[2], al[2];
#pragma unroll
        for (int mt = 0; mt < 2; ++mt) {
            ah[mt] = *(const f16x8*)(lds + mt * 1024 + lane * 16);
            al[mt] = *(const f16x8*)(lds + LDS_ALO + mt * 1024 + lane * 16);
        }
        const char* bb = lds + LDS_B + ncol * 1024 + lane * 16;
        f16x8 bqh = *(const f16x8*)(bb + 0 * 8192);
        f16x8 bql = *(const f16x8*)(bb + 1 * 8192);
        f16x8 bkh = *(const f16x8*)(bb + 2 * 8192);
        f16x8 bkl = *(const f16x8*)(bb + 3 * 8192);
#pragma unroll
        for (int mt = 0; mt < 2; ++mt) {
            accq[mt] = MFMA(ah[mt], bqh, accq[mt]);
            accq[mt] = MFMA(al[mt], bqh, accq[mt]);
            accq[mt] = MFMA(ah[mt], bql, accq[mt]);
            acck[mt] = MFMA(ah[mt], bkh, acck[mt]);
            acck[mt] = MFMA(al[mt], bkh, acck[mt]);
            acck[mt] = MFMA(ah[mt], bkl, acck[mt]);
        }
    }

    float* part    = (float*)(lds + 36864);
    float* combmax = (float*)(lds + 36864 + 2048);
    float* combsum = (float*)(lds + 36864 + 2304);

#pragma unroll
    for (int mt = 0; mt < 2; ++mt)
#pragma unroll
        for (int r = 0; r < 16; ++r) {
            const int rl = (r & 3) + 8 * (r >> 2) + 4 * h;
            const int hh = h0 + mt * 32 + rl;
            const int vv = ncol * 32 + l31;
            const size_t bidx = ((size_t)c * Hn + hh) * Wn + vv;
            const float qv = accq[mt][r] + bq[bidx];
            const float kv = acck[mt][r] + bk[bidx];
            accq[mt][r] = qv * kv;
        }

#pragma unroll
    for (int mt = 0; mt < 2; ++mt)
#pragma unroll
        for (int r = 0; r < 16; ++r) {
            float m2 = accq[mt][r];
#pragma unroll
            for (int off = 16; off > 0; off >>= 1)
                m2 = fmaxf(m2, __shfl_xor(m2, off, 64));
            if ((lane & 15) == r && ((lane >> 4) & 1) == mt) {
                const int rl  = (r & 3) + 8 * (r >> 2) + 4 * h;
                const int row = mt * 32 + rl;
                part[ncol * 64 + row] = m2;
            }
        }
    __syncthreads();
    if (tid < 64) {
        float m = part[tid];
#pragma unroll
        for (int w = 1; w < 8; ++w)
            m = fmaxf(m, part[w * 64 + tid]);
        combmax[tid] = m;
    }
    __syncthreads();

#pragma unroll
    for (int mt = 0; mt < 2; ++mt)
#pragma unroll
        for (int r = 0; r < 16; ++r) {
            const int rl  = (r & 3) + 8 * (r >> 2) + 4 * h;
            const int row = mt * 32 + rl;
            const float mx = combmax[row];
            const float e0 = __expf(accq[mt][r] - mx);
            accq[mt][r] = e0;
            float ps = e0;
#pragma unroll
            for (int off = 16; off > 0; off >>= 1)
                ps += __shfl_xor(ps, off, 64);
            if ((lane & 15) == r && ((lane >> 4) & 1) == mt)
                part[ncol * 64 + row] = ps;
        }
    __syncthreads();
    if (tid < 64) {
        float s = part[tid];
#pragma unroll
        for (int w = 1; w < 8; ++w)
            s += part[w * 64 + tid];
        combsum[tid] = s;
    }

    f32x16 accv[2];
#pragma unroll
    for (int mt = 0; mt < 2; ++mt)
#pragma unroll
        for (int r = 0; r < 16; ++r)
            accv[mt][r] = 0.f;

    for (int kt = 0; kt < 16; ++kt) {
        const int k0 = kt * 16;
        __syncthreads();
        {
            const float* wrow = w_v + (size_t)(k0 + wkh * 8) * Wn + n;
            float w8[8];
#pragma unroll
            for (int r = 0; r < 8; ++r)
                w8[r] = wrow[(size_t)r * Wn];
            f16x8 hi8;
#pragma unroll
            for (int e = 0; e < 8; ++e)
                hi8[e] = (_Float16)w8[e];
            *(f16x8*)(lds + LDS_B + ntW * 1024 + wfo) = hi8;
        }
        if (tid < 256) {
            const float4 xx = *(const float4*)(xbase + (size_t)am * Wn + k0 + akq * 4);
            f16x4 hi4;
            hi4[0] = (_Float16)xx.x;
            hi4[1] = (_Float16)xx.y;
            hi4[2] = (_Float16)xx.z;
            hi4[3] = (_Float16)xx.w;
            *(f16x4*)(lds + amt * 1024 + alc * 16 + aboff) = hi4;
        }
        __syncthreads();

        f16x8 ah[2];
#pragma unroll
        for (int mt = 0; mt < 2; ++mt)
            ah[mt] = *(const f16x8*)(lds + mt * 1024 + lane * 16);
        f16x8 bvh = *(const f16x8*)(lds + LDS_B + ncol * 1024 + lane * 16);
#pragma unroll
        for (int mt = 0; mt < 2; ++mt)
            accv[mt] = MFMA(ah[mt], bvh, accv[mt]);
    }

    float* obase = out + ((size_t)(b * Cn + c) * Hn) * Wn;
#pragma unroll
    for (int mt = 0; mt < 2; ++mt)
#pragma unroll
        for (int r = 0; r < 16; ++r) {
            const int rl  = (r & 3) + 8 * (r >> 2) + 4 * h;
            const int row = mt * 32 + rl;
            const float inv = 1.0f / combsum[row];
            const int hh = h0 + row;
            const int vv = ncol * 32 + l31;
            const size_t bidx = ((size_t)c * Hn + hh) * Wn + vv;
            const float vx = accv[mt][r] + bv[bidx];
            obase[(size_t)hh * Wn + vv] = accq[mt][r] * vx * inv;
        }
}

extern "C" void kernel_launch(void* const* d_in, const int* in_sizes, int n_in,
                              void* d_out, int out_size, void* d_ws, size_t ws_size,
                              hipStream_t stream) {
    (void)in_sizes; (void)n_in; (void)out_size;
    const float* x  = (const float*)d_in[0];
    const float* wq = (const float*)d_in[1];
    const float* wk = (const float*)d_in[2];
    const float* wv = (const float*)d_in[3];
    const float* bq = (const float*)d_in[4];
    const float* bk = (const float*)d_in[5];
    const float* bv = (const float*)d_in[6];
    float* out = (float*)d_out;

    if (d_ws != nullptr && ws_size >= WS_NEED) {
        hipLaunchKernelGGL(prep_w, dim3(Cn * 16), dim3(256), 0, stream,
                           wq, wk, wv, (_Float16*)d_ws);
        hipLaunchKernelGGL(axile_attn_fused, dim3(Bn * 8 * Cn), dim3(512), 0, stream,
                           x, (const _Float16*)d_ws, bq, bk, bv, out);
    } else {
        hipLaunchKernelGGL(axile_attn_mfma4, dim3(Bn * 4 * Cn), dim3(512), 0, stream,
                           x, wq, wk, wv, bq, bk, bv, out);
    }
}